// Round 1
// baseline (925.962 us; speedup 1.0000x reference)
//
#include <hip/hip_runtime.h>

#define B_SZ  4096
#define T_LEN 1024
#define VOCAB 32000
#define HID   16

__device__ __forceinline__ float fast_tanh(float x) {
  float ax = fabsf(x);
  float e  = __expf(2.0f * ax);            // v_mul + v_exp
  float r  = __fdividef(2.0f, e + 1.0f);   // fast reciprocal path
  float t  = 1.0f - r;
  return x < 0.0f ? -t : t;                // tanh(inf) handled: r->0, t->1
}

// E2[v][i] = sum_j Wx_w[i][j] * embed[v][j] + Wx_b[i]
__global__ __launch_bounds__(256) void e2_kernel(
    const float* __restrict__ embed, const float* __restrict__ Wxw,
    const float* __restrict__ Wxb, float* __restrict__ E2) {
  int tid = blockIdx.x * 256 + threadIdx.x;   // 512000 threads
  int v = tid >> 4, i = tid & 15;
  const float4* er = (const float4*)(embed + (size_t)v * HID);
  const float4* wr = (const float4*)(Wxw + (size_t)i * HID);
  float acc = Wxb[i];
#pragma unroll
  for (int q = 0; q < 4; ++q) {
    float4 e4 = er[q], w4 = wr[q];
    acc = fmaf(w4.x, e4.x, acc);
    acc = fmaf(w4.y, e4.y, acc);
    acc = fmaf(w4.z, e4.z, acc);
    acc = fmaf(w4.w, e4.w, acc);
  }
  E2[tid] = acc;
}

// One chain per 16 lanes; h replicated across the 16 lanes.
// Lane i owns Wh row i; per step: 16 FMA dot, tanh, 16-lane re-broadcast.
__global__ __launch_bounds__(256) void rnn_kernel(
    const int* __restrict__ seq, const float* __restrict__ E2,
    const float* __restrict__ Wh, float* __restrict__ hfin) {
  int tid = blockIdx.x * 256 + threadIdx.x;   // 65536 threads
  int b = tid >> 4, i = tid & 15;

  float wh[16];
  const float4* whr = (const float4*)(Wh + (size_t)i * HID);
#pragma unroll
  for (int q = 0; q < 4; ++q) {
    float4 w4 = whr[q];
    wh[4*q+0] = w4.x; wh[4*q+1] = w4.y; wh[4*q+2] = w4.z; wh[4*q+3] = w4.w;
  }

  float h[16];
#pragma unroll
  for (int j = 0; j < 16; ++j) h[j] = 0.0f;

  const int4* seq4 = (const int4*)(seq + (size_t)b * T_LEN);

  // 2-deep pipeline: idxN holds indices for group g+1; xpA holds xp for group g.
  float xpA[4];
  int4 idxN;
  {
    int4 i0 = seq4[0];
    idxN = seq4[1];
    xpA[0] = E2[i0.x * HID + i];
    xpA[1] = E2[i0.y * HID + i];
    xpA[2] = E2[i0.z * HID + i];
    xpA[3] = E2[i0.w * HID + i];
  }

  for (int g = 0; g < T_LEN / 4; ++g) {
    int gn = (g + 2 < T_LEN / 4) ? (g + 2) : (T_LEN / 4 - 1);
    int4 idxF = seq4[gn];                    // prefetch idx for group g+2
    float xpB[4];                            // prefetch xp for group g+1
    xpB[0] = E2[idxN.x * HID + i];
    xpB[1] = E2[idxN.y * HID + i];
    xpB[2] = E2[idxN.z * HID + i];
    xpB[3] = E2[idxN.w * HID + i];

#pragma unroll
    for (int s = 0; s < 4; ++s) {
      float acc = xpA[s];
#pragma unroll
      for (int j = 0; j < 16; ++j) acc = fmaf(wh[j], h[j], acc);
      float hn = fast_tanh(acc);
#pragma unroll
      for (int j = 0; j < 16; ++j) h[j] = __shfl(hn, j, 16);
    }

#pragma unroll
    for (int s = 0; s < 4; ++s) xpA[s] = xpB[s];
    idxN = idxF;
  }

  hfin[(size_t)b * HID + i] = h[i];          // every lane has full h; write own elem
}

// out[b][v] = sum_i hfin[b][i]*out_w[v][i] + out_b[v]
// Lane owns 4 consecutive v (64 out_w values in regs); wave covers 256 v;
// each wave loops over 16 rows; float4 coalesced stores.
__global__ __launch_bounds__(256) void out_gemm(
    const float* __restrict__ hfin, const float* __restrict__ outw,
    const float* __restrict__ outb, float* __restrict__ out) {
  int lane = threadIdx.x & 63;
  int wv   = threadIdx.x >> 6;
  int v0 = blockIdx.x * 256 + lane * 4;
  int b0 = blockIdx.y * 64 + wv * 16;

  float w[4][16];
#pragma unroll
  for (int c = 0; c < 4; ++c) {
    const float4* wr = (const float4*)(outw + (size_t)(v0 + c) * HID);
#pragma unroll
    for (int q = 0; q < 4; ++q) {
      float4 t = wr[q];
      w[c][4*q+0] = t.x; w[c][4*q+1] = t.y; w[c][4*q+2] = t.z; w[c][4*q+3] = t.w;
    }
  }
  float4 ob = *(const float4*)(outb + v0);

  for (int r = 0; r < 16; ++r) {
    int b = b0 + r;
    const float4* hr = (const float4*)(hfin + (size_t)b * HID);
    float hv[16];
#pragma unroll
    for (int q = 0; q < 4; ++q) {
      float4 t = hr[q];
      hv[4*q+0] = t.x; hv[4*q+1] = t.y; hv[4*q+2] = t.z; hv[4*q+3] = t.w;
    }
    float4 acc = ob;
#pragma unroll
    for (int k = 0; k < 16; ++k) {
      acc.x = fmaf(w[0][k], hv[k], acc.x);
      acc.y = fmaf(w[1][k], hv[k], acc.y);
      acc.z = fmaf(w[2][k], hv[k], acc.z);
      acc.w = fmaf(w[3][k], hv[k], acc.w);
    }
    *(float4*)(out + (size_t)b * VOCAB + v0) = acc;
  }
}

extern "C" void kernel_launch(void* const* d_in, const int* in_sizes, int n_in,
                              void* d_out, int out_size, void* d_ws, size_t ws_size,
                              hipStream_t stream) {
  const int*   seq   = (const int*)  d_in[0];
  const float* embed = (const float*)d_in[1];
  const float* Wh    = (const float*)d_in[2];
  const float* Wxw   = (const float*)d_in[3];
  const float* Wxb   = (const float*)d_in[4];
  const float* outw  = (const float*)d_in[5];
  const float* outb  = (const float*)d_in[6];
  float* out  = (float*)d_out;

  float* E2   = (float*)d_ws;                        // 32000*16 fp32 = 2.048 MB
  float* hfin = (float*)d_ws + (size_t)VOCAB * HID;  // 4096*16 fp32 = 256 KB

  e2_kernel<<<VOCAB * HID / 256, 256, 0, stream>>>(embed, Wxw, Wxb, E2);
  rnn_kernel<<<B_SZ * HID / 256, 256, 0, stream>>>(seq, E2, Wh, hfin);
  dim3 grid(VOCAB / 256, B_SZ / 64);
  out_gemm<<<grid, dim3(256), 0, stream>>>(hfin, outw, outb, out);
}